// Round 22
// baseline (54.712 us; speedup 1.0000x reference)
//
#include <hip/hip_runtime.h>

// AttentionConvFull: grouped 1x1 QKV + 5x5 per-channel local attention, FUSED.
// B=4, H=W=56, C=OC=256, G=8, Cg=32, K=5, pad=2.
//
// R22 insight (R12/R16/R21 ledger): VGPR_Count pinned at 72 regardless of
// phase-C diets => peak is the merged pass, AND the HW allocation quantum
// steps at 64/128 (m68/m69) => anything in 65..128 has IDENTICAL occupancy.
// So spend the ~50 free regs on ILP instead of dieting:
//   Merged pass: 2 PIXELS PER ITER (9 iters), 6 independent FMA chains,
//   16 b128 LDS loads pipelined per iter, each demoted-weight L1 reload
//   serves 2 pixels (halves reload traffic). Unlike R13 (which spilled),
//   weights stay SCALAR arrays (compiler demotes them to L1 - that's fine);
//   demand ~85-95 < cap 128 under (256,2).
//   Phase C: R16 shape with qreg[8] restored (free headroom).
//
//   Stage:   x halo (12x12 px, 32 ch) -> xs LDS, coalesced float4, OOB zeroed.
//   Merged QKV pass: k,v packed bf16x2 in one u32, overwriting xs in place
//            (both rows of an iter owned by the same half-wave; all reads
//            precede writes; per-wave in-order DS => race-free).
//            q*log2e -> qs (f32).
//   Phase C: monolithic 8-pixel row-streaming attention; k,v,rel bf16-
//            unpacked on use; native exp2 + rcp; single-pass softmax.
// 2 barriers. LDS 26.6 KB.
//
// Register law (R1-R21): cap = 256/N for __launch_bounds__(256,N); no bounds
// => 64 cap. Forced caps below demand spill (WRITE >> 12.5MB logical).
// launch_bounds 2nd arg does NOT limit residency (R20). Occupancy bands are
// quantized: <=64 / <=128 / <=256 (m69) - 65..128 all equivalent.
// Precision ledger: bf16 k,v + bf16 rel = 2.34e-2 measured; threshold 5.69e-2.

constexpr int TB = 4, TH = 56, TW = 56, TC = 256;
constexpr int G  = 8, CG = 32, PAD = 2;
constexpr int TILE = 8;
constexpr int HT = TILE + 2 * PAD;   // 12
constexpr int NT = TH / TILE;        // 7
constexpr int NPIX_HALO = HT * HT;   // 144
constexpr float LOG2E = 1.44269504088896340736f;

__global__ __launch_bounds__(256, 2)
void fused_attn_conv_kernel(const float* __restrict__ x,
                            const float* __restrict__ wq,
                            const float* __restrict__ wk,
                            const float* __restrict__ wv,
                            const float* __restrict__ rel,
                            const float* __restrict__ qemb,
                            float* __restrict__ out) {
    __shared__ float xs[NPIX_HALO][CG];    // 18 KB: x halo, then packed bf16(k,v)
    __shared__ float qs[TILE * TILE][CG];  // 8 KB: q*log2e for interior pixels

    const int bid  = blockIdx.x;
    const int g    = bid & 7;
    const int tile = bid >> 3;
    const int tj   = tile % NT;
    const int ti   = (tile / NT) % NT;
    const int b    = tile / (NT * NT);

    const int t  = threadIdx.x;
    const int c  = t & 31;
    const int p0 = t >> 5;

    const int oc = g * CG + c;           // global out-channel
    const int h0 = ti * TILE - PAD, w0 = tj * TILE - PAD;

    // ---- Stage: x halo -> xs, coalesced float4 (1152 float4 over 256 thr).
#pragma unroll
    for (int r = 0; r < 5; ++r) {
        const int f = t + r * 256;
        if (f < NPIX_HALO * CG / 4) {
            const int hp = f >> 3, c4 = f & 7;        // 8 float4 per pixel
            const int hi = hp / HT, hj = hp % HT;
            const int gh = h0 + hi, gw = w0 + hj;
            float4 val = make_float4(0.f, 0.f, 0.f, 0.f);
            if (gh >= 0 && gh < TH && gw >= 0 && gw < TW)
                val = *(const float4*)(x + (((size_t)b * TH + gh) * TW + gw) * TC
                                         + g * CG + c4 * 4);
            *(float4*)&xs[hp][c4 * 4] = val;
        }
    }

    __syncthreads();   // stage -> merged pass

    // ---- Merged QKV pass, 2 pixels/iter (9 iters), 6 chains.
    {
        float wqr[CG], wkr[CG], wvr[CG];   // scalar: compiler demotes to L1
        const float4* wqp = (const float4*)(wq + (size_t)oc * CG);
        const float4* wkp = (const float4*)(wk + (size_t)oc * CG);
        const float4* wvp = (const float4*)(wv + (size_t)oc * CG);
#pragma unroll
        for (int i = 0; i < CG / 4; ++i) {
            float4 a = wqp[i], bb = wkp[i], cc = wvp[i];
            wqr[4*i+0]=a.x; wqr[4*i+1]=a.y; wqr[4*i+2]=a.z; wqr[4*i+3]=a.w;
            wkr[4*i+0]=bb.x; wkr[4*i+1]=bb.y; wkr[4*i+2]=bb.z; wkr[4*i+3]=bb.w;
            wvr[4*i+0]=cc.x; wvr[4*i+1]=cc.y; wvr[4*i+2]=cc.z; wvr[4*i+3]=cc.w;
        }
        const float qe = qemb[oc];

#pragma unroll 1
        for (int it = 0; it < 9; ++it) {
            const int hpA = it * 16 + p0;        // both rows owned by group p0
            const int hpB = hpA + 8;
            const float4* xpA = (const float4*)&xs[hpA][0];
            const float4* xpB = (const float4*)&xs[hpB][0];
            float aqA = qe, akA = 0.f, avA = 0.f;
            float aqB = qe, akB = 0.f, avB = 0.f;
#pragma unroll
            for (int i = 0; i < CG / 4; ++i) {
                const float4 xa = xpA[i];
                const float4 xb = xpB[i];
                const float w0q = wqr[4*i+0], w0k = wkr[4*i+0], w0v = wvr[4*i+0];
                aqA = fmaf(w0q, xa.x, aqA); akA = fmaf(w0k, xa.x, akA); avA = fmaf(w0v, xa.x, avA);
                aqB = fmaf(w0q, xb.x, aqB); akB = fmaf(w0k, xb.x, akB); avB = fmaf(w0v, xb.x, avB);
                const float w1q = wqr[4*i+1], w1k = wkr[4*i+1], w1v = wvr[4*i+1];
                aqA = fmaf(w1q, xa.y, aqA); akA = fmaf(w1k, xa.y, akA); avA = fmaf(w1v, xa.y, avA);
                aqB = fmaf(w1q, xb.y, aqB); akB = fmaf(w1k, xb.y, akB); avB = fmaf(w1v, xb.y, avB);
                const float w2q = wqr[4*i+2], w2k = wkr[4*i+2], w2v = wvr[4*i+2];
                aqA = fmaf(w2q, xa.z, aqA); akA = fmaf(w2k, xa.z, akA); avA = fmaf(w2v, xa.z, avA);
                aqB = fmaf(w2q, xb.z, aqB); akB = fmaf(w2k, xb.z, akB); avB = fmaf(w2v, xb.z, avB);
                const float w3q = wqr[4*i+3], w3k = wkr[4*i+3], w3v = wvr[4*i+3];
                aqA = fmaf(w3q, xa.w, aqA); akA = fmaf(w3k, xa.w, akA); avA = fmaf(w3v, xa.w, avA);
                aqB = fmaf(w3q, xb.w, aqB); akB = fmaf(w3k, xb.w, akB); avB = fmaf(w3v, xb.w, avB);
            }
            // pack k,v -> bf16 (round-half-up) in one u32; overwrite rows in
            // place (all reads above precede these writes, same owning lanes).
            const unsigned kbA = __float_as_uint(akA) + 0x8000u;
            const unsigned vbA = __float_as_uint(avA) + 0x8000u;
            ((unsigned*)&xs[hpA][0])[c] = (kbA >> 16) | (vbA & 0xffff0000u);
            const unsigned kbB = __float_as_uint(akB) + 0x8000u;
            const unsigned vbB = __float_as_uint(avB) + 0x8000u;
            ((unsigned*)&xs[hpB][0])[c] = (kbB >> 16) | (vbB & 0xffff0000u);

            const int hiA = hpA / HT, hjA = hpA % HT;
            if (hiA >= PAD && hiA < PAD + TILE && hjA >= PAD && hjA < PAD + TILE)
                qs[(hiA - PAD) * TILE + (hjA - PAD)][c] = aqA * LOG2E;
            const int hiB = hpB / HT, hjB = hpB % HT;
            if (hiB >= PAD && hiB < PAD + TILE && hjB >= PAD && hjB < PAD + TILE)
                qs[(hiB - PAD) * TILE + (hjB - PAD)][c] = aqB * LOG2E;
        }
    }

    // rel row -> 13 packed bf16 pairs (even idx = low half, odd = high half)
    unsigned relp[13];
    {
        const float* rp = rel + (size_t)oc * 25;
#pragma unroll
        for (int i = 0; i < 12; ++i) {
            const unsigned lo = __float_as_uint(rp[2 * i])     + 0x8000u;
            const unsigned hi = __float_as_uint(rp[2 * i + 1]) + 0x8000u;
            relp[i] = (lo >> 16) | (hi & 0xffff0000u);
        }
        relp[12] = (__float_as_uint(rp[24]) + 0x8000u) >> 16;
    }

    __syncthreads();   // merged pass -> C

    // q (already *log2e) for this thread's 8 column pixels
    float qreg[8];
#pragma unroll
    for (int ii = 0; ii < 8; ++ii) qreg[ii] = qs[ii * TILE + p0][c];

    // ---- Phase C: monolithic row-streaming attention (xs holds bf16 k,v).
    float s_[8], a_[8];
#pragma unroll
    for (int ii = 0; ii < 8; ++ii) { s_[ii] = 0.f; a_[ii] = 0.f; }

    const unsigned* kvp = (const unsigned*)&xs[0][0];
#pragma unroll
    for (int h = 0; h < HT; ++h) {
        float kr[5], vr[5];
#pragma unroll
        for (int j = 0; j < 5; ++j) {
            const unsigned u = kvp[(h * HT + p0 + j) * CG + c];
            kr[j] = __uint_as_float(u << 16);          // bf16 k -> f32
            vr[j] = __uint_as_float(u & 0xffff0000u);  // bf16 v -> f32
        }
#pragma unroll
        for (int ii = 0; ii < 8; ++ii) {
            const int di = h - ii;               // compile-time after unroll
            if (di >= 0 && di < 5) {
                const float qv = qreg[ii];
#pragma unroll
                for (int j = 0; j < 5; ++j) {
                    const int idx = di * 5 + j;  // compile-time
                    const unsigned ru = relp[idx >> 1];
                    const float rl = __uint_as_float((idx & 1) ? (ru & 0xffff0000u)
                                                               : (ru << 16));
                    const float e = __builtin_amdgcn_exp2f(qv * (kr[j] + rl));
                    s_[ii] += e;
                    a_[ii] = fmaf(e, vr[j], a_[ii]);
                }
            }
        }
    }

#pragma unroll
    for (int ii = 0; ii < 8; ++ii) {
        const int gh = ti * TILE + ii, gw = tj * TILE + p0;
        out[(((size_t)b * TH + gh) * TW + gw) * TC + g * CG + c] =
            a_[ii] * __builtin_amdgcn_rcpf(s_[ii]);
    }
}

extern "C" void kernel_launch(void* const* d_in, const int* in_sizes, int n_in,
                              void* d_out, int out_size, void* d_ws, size_t ws_size,
                              hipStream_t stream) {
    const float* x    = (const float*)d_in[0];
    const float* wq   = (const float*)d_in[1];
    const float* wk   = (const float*)d_in[2];
    const float* wv   = (const float*)d_in[3];
    const float* rel  = (const float*)d_in[4];
    const float* qemb = (const float*)d_in[5];
    float* out = (float*)d_out;

    const int nblocks = TB * NT * NT * G;   // 4*7*7*8 = 1568
    hipLaunchKernelGGL(fused_attn_conv_kernel, dim3(nblocks), dim3(256), 0, stream,
                       x, wq, wk, wv, rel, qemb, out);
}

// Round 23
// 40.948 us; speedup vs baseline: 1.3361x; 1.3361x over previous
//
#include <hip/hip_runtime.h>

// AttentionConvFull: grouped 1x1 QKV + 5x5 per-channel local attention, FUSED.
// B=4, H=W=56, C=OC=256, G=8, Cg=32, K=5, pad=2.
//
// R23: projection moved to MFMA (mfma_f32_16x16x32_f16). Per block the
// projection is A[144x32] (x halo, f16) x B[32x96] (wq|wk|wv transposed,
// f16) = D[144x96] -> 54 MFMA ops total (~14/wave) vs 3456 VALU cyc/wave
// in the scalar design (R12-R22 plateau at 52-60us, MfmaUtil 0).
// f16 inputs precision-validated by R19 (fdot2-f16 projection: same absmax
// 2.34e-2). M=144=9x16 exact. B-frags read straight from w's [oc][ic]
// layout (B[k][col]=w[col][k] is k-contiguous). D mapping (m89-verified):
// col=lane&15, row=(lane>>4)*4+reg. k,v D-tiles pack to bf16 pairs in-lane.
//   Stage:   x halo -> xs16 (f16 pairs) + w group-slices -> wTs (f16).
//   MFMA:    wave wv does M-tiles {wv, wv+4, wv+8}; 6 B-frags hoisted;
//            q (f32, *log2e) -> qs for interior px; (k,v) bf16-packed -> kvs.
//   Phase C: champion R16/R20 row-streaming attention, UNCHANGED.
// LDS: xs16 9K + wTs 6K + kvs 18K + qs 8K = 41 KB. 2 barriers.
//
// Register law (R1-R22): cap = 256/N for __launch_bounds__(256,N); forced
// caps below demand spill (WRITE >> 12.5MB logical). Occupancy tracks VGPR
// finer than 64/128 bands (R22: 72->88 cost 24%->17%). Spill check:
// VGPR==cap AND WRITE >> 12.5MB.
// Precision ledger: f16 proj + bf16 k,v + bf16 rel = 2.34e-2 (R19);
// threshold 5.69e-2.

constexpr int TB = 4, TH = 56, TW = 56, TC = 256;
constexpr int G  = 8, CG = 32, PAD = 2;
constexpr int TILE = 8;
constexpr int HT = TILE + 2 * PAD;   // 12
constexpr int NT = TH / TILE;        // 7
constexpr int NPIX_HALO = HT * HT;   // 144
constexpr float LOG2E = 1.44269504088896340736f;

typedef __fp16 half2_t __attribute__((ext_vector_type(2)));
typedef __fp16 half8   __attribute__((ext_vector_type(8)));
typedef float  f32x4   __attribute__((ext_vector_type(4)));

__device__ __forceinline__ unsigned h2u(half2_t h) {
    union { half2_t h; unsigned u; } cv; cv.h = h; return cv.u;
}
__device__ __forceinline__ unsigned packbf(float k, float v) {
    return ((__float_as_uint(k) + 0x8000u) >> 16) |
           ((__float_as_uint(v) + 0x8000u) & 0xffff0000u);
}

__global__ __launch_bounds__(256, 2)
void fused_attn_conv_kernel(const float* __restrict__ x,
                            const float* __restrict__ wq,
                            const float* __restrict__ wk,
                            const float* __restrict__ wv,
                            const float* __restrict__ rel,
                            const float* __restrict__ qemb,
                            float* __restrict__ out) {
    __shared__ __align__(16) __fp16 xs16[NPIX_HALO][CG];  // 9 KB: x halo f16
    __shared__ __align__(16) __fp16 wTs[3 * CG][CG];      // 6 KB: rows: q|k|v oc, cols: ic
    __shared__ unsigned kvs[NPIX_HALO][CG];               // 18 KB: packed bf16 (k,v)
    __shared__ float    qs[TILE * TILE][CG];              // 8 KB: q*log2e (interior)

    const int bid  = blockIdx.x;
    const int g    = bid & 7;
    const int tile = bid >> 3;
    const int tj   = tile % NT;
    const int ti   = (tile / NT) % NT;
    const int b    = tile / (NT * NT);

    const int t  = threadIdx.x;
    const int c  = t & 31;
    const int p0 = t >> 5;

    const int oc = g * CG + c;           // global out-channel (phase C)
    const int h0 = ti * TILE - PAD, w0 = tj * TILE - PAD;

    // ---- Stage x halo -> xs16 (f16 pairs). 2304 u32 = 9/thread, coalesced.
    unsigned (*xsu)[CG / 2] = (unsigned(*)[CG / 2])xs16;
#pragma unroll
    for (int r = 0; r < 9; ++r) {
        const int f  = t + r * 256;          // 0..2303
        const int px = f >> 4, pr = f & 15;  // 16 channel-pairs per pixel
        const int hi = px / HT, hj = px % HT;
        const int gh = h0 + hi, gw = w0 + hj;
        unsigned val = 0u;
        if (gh >= 0 && gh < TH && gw >= 0 && gw < TW) {
            const float2 xv = *(const float2*)(x + (((size_t)b * TH + gh) * TW + gw) * TC
                                                 + g * CG + pr * 2);
            val = h2u(__builtin_amdgcn_cvt_pkrtz(xv.x, xv.y));
        }
        xsu[px][pr] = val;
    }

    // ---- Stage weights -> wTs (f16). Rows 0-31 wq, 32-63 wk, 64-95 wv.
    {
        unsigned (*wTu)[CG / 2] = (unsigned(*)[CG / 2])wTs;
        const float* wsrc[3] = {wq, wk, wv};
#pragma unroll
        for (int m = 0; m < 3; ++m) {
#pragma unroll
            for (int r = 0; r < 2; ++r) {
                const int f = t + r * 256;           // 0..511 float2 idx
                const int row = f >> 4, pr = f & 15; // row=oc 0..31
                const float2 wv2 = *(const float2*)(wsrc[m] + ((size_t)(g * CG + row)) * CG
                                                            + pr * 2);
                wTu[m * CG + row][pr] = h2u(__builtin_amdgcn_cvt_pkrtz(wv2.x, wv2.y));
            }
        }
    }

    __syncthreads();   // stage -> MFMA

    // ---- MFMA projection: D[144x96] = A[144x32] x B[32x96].
    //      A frag: lane holds A[row=lw&15][k=(lw>>4)*8+j]  (half8 = 1 b128)
    //      B frag: lane holds B[k=(lw>>4)*8+j][col=lw&15]  = wTs[col][k]
    //      D:      col=lane&15, row=(lane>>4)*4+reg   (m89-verified)
    {
        const int wvid = t >> 6, lw = t & 63;
        const int lcol = lw & 15;
        const int lko  = (lw >> 4) * 8;
        const half8 bq0 = *(const half8*)&wTs[ 0 + lcol][lko];
        const half8 bq1 = *(const half8*)&wTs[16 + lcol][lko];
        const half8 bk0 = *(const half8*)&wTs[32 + lcol][lko];
        const half8 bk1 = *(const half8*)&wTs[48 + lcol][lko];
        const half8 bv0 = *(const half8*)&wTs[64 + lcol][lko];
        const half8 bv1 = *(const half8*)&wTs[80 + lcol][lko];
        const float qeL = qemb[g * CG + lcol];        // q_emb for cols 0-15
        const float qeH = qemb[g * CG + lcol + 16];   // and cols 16-31
        const f32x4 z4 = {0.f, 0.f, 0.f, 0.f};

#pragma unroll 1
        for (int mt = wvid; mt < 9; mt += 4) {        // waves: 3/2/2/2 M-tiles
            const half8 a = *(const half8*)&xs16[mt * 16 + lcol][lko];
            const f32x4 dq0 = __builtin_amdgcn_mfma_f32_16x16x32_f16(a, bq0, z4, 0, 0, 0);
            const f32x4 dq1 = __builtin_amdgcn_mfma_f32_16x16x32_f16(a, bq1, z4, 0, 0, 0);
            const f32x4 dk0 = __builtin_amdgcn_mfma_f32_16x16x32_f16(a, bk0, z4, 0, 0, 0);
            const f32x4 dk1 = __builtin_amdgcn_mfma_f32_16x16x32_f16(a, bk1, z4, 0, 0, 0);
            const f32x4 dv0 = __builtin_amdgcn_mfma_f32_16x16x32_f16(a, bv0, z4, 0, 0, 0);
            const f32x4 dv1 = __builtin_amdgcn_mfma_f32_16x16x32_f16(a, bv1, z4, 0, 0, 0);
            const int prow = mt * 16 + ((lw >> 4) << 2);
#pragma unroll
            for (int j = 0; j < 4; ++j) {
                const int px = prow + j;
                kvs[px][lcol]      = packbf(dk0[j], dv0[j]);
                kvs[px][lcol + 16] = packbf(dk1[j], dv1[j]);
                const int hi2 = px / HT, hj2 = px % HT;
                if (hi2 >= PAD && hi2 < PAD + TILE && hj2 >= PAD && hj2 < PAD + TILE) {
                    const int qp = (hi2 - PAD) * TILE + (hj2 - PAD);
                    qs[qp][lcol]      = (dq0[j] + qeL) * LOG2E;
                    qs[qp][lcol + 16] = (dq1[j] + qeH) * LOG2E;
                }
            }
        }
    }

    // rel row -> 13 packed bf16 pairs (even idx = low half, odd = high half)
    unsigned relp[13];
    {
        const float* rp = rel + (size_t)oc * 25;
#pragma unroll
        for (int i = 0; i < 12; ++i) {
            const unsigned lo = __float_as_uint(rp[2 * i])     + 0x8000u;
            const unsigned hi = __float_as_uint(rp[2 * i + 1]) + 0x8000u;
            relp[i] = (lo >> 16) | (hi & 0xffff0000u);
        }
        relp[12] = (__float_as_uint(rp[24]) + 0x8000u) >> 16;
    }

    __syncthreads();   // MFMA -> phase C

    // q (already *log2e) for this thread's 8 column pixels
    float qreg[8];
#pragma unroll
    for (int ii = 0; ii < 8; ++ii) qreg[ii] = qs[ii * TILE + p0][c];

    // ---- Phase C: monolithic row-streaming attention (champion R16/R20).
    float s_[8], a_[8];
#pragma unroll
    for (int ii = 0; ii < 8; ++ii) { s_[ii] = 0.f; a_[ii] = 0.f; }

    const unsigned* kvp = (const unsigned*)&kvs[0][0];
#pragma unroll
    for (int h = 0; h < HT; ++h) {
        float kr[5], vr[5];
#pragma unroll
        for (int j = 0; j < 5; ++j) {
            const unsigned u = kvp[(h * HT + p0 + j) * CG + c];
            kr[j] = __uint_as_float(u << 16);          // bf16 k -> f32
            vr[j] = __uint_as_float(u & 0xffff0000u);  // bf16 v -> f32
        }
#pragma unroll
        for (int ii = 0; ii < 8; ++ii) {
            const int di = h - ii;               // compile-time after unroll
            if (di >= 0 && di < 5) {
                const float qv = qreg[ii];
#pragma unroll
                for (int j = 0; j < 5; ++j) {
                    const int idx = di * 5 + j;  // compile-time
                    const unsigned ru = relp[idx >> 1];
                    const float rl = __uint_as_float((idx & 1) ? (ru & 0xffff0000u)
                                                               : (ru << 16));
                    const float e = __builtin_amdgcn_exp2f(qv * (kr[j] + rl));
                    s_[ii] += e;
                    a_[ii] = fmaf(e, vr[j], a_[ii]);
                }
            }
        }
    }

#pragma unroll
    for (int ii = 0; ii < 8; ++ii) {
        const int gh = ti * TILE + ii, gw = tj * TILE + p0;
        out[(((size_t)b * TH + gh) * TW + gw) * TC + g * CG + c] =
            a_[ii] * __builtin_amdgcn_rcpf(s_[ii]);
    }
}

extern "C" void kernel_launch(void* const* d_in, const int* in_sizes, int n_in,
                              void* d_out, int out_size, void* d_ws, size_t ws_size,
                              hipStream_t stream) {
    const float* x    = (const float*)d_in[0];
    const float* wq   = (const float*)d_in[1];
    const float* wk   = (const float*)d_in[2];
    const float* wv   = (const float*)d_in[3];
    const float* rel  = (const float*)d_in[4];
    const float* qemb = (const float*)d_in[5];
    float* out = (float*)d_out;

    const int nblocks = TB * NT * NT * G;   // 4*7*7*8 = 1568
    hipLaunchKernelGGL(fused_attn_conv_kernel, dim3(nblocks), dim3(256), 0, stream,
                       x, wq, wk, wv, rel, qemb, out);
}

// Round 24
// 40.198 us; speedup vs baseline: 1.3611x; 1.0187x over previous
//
#include <hip/hip_runtime.h>

// AttentionConvFull: grouped 1x1 QKV + 5x5 per-channel local attention, FUSED.
// B=4, H=W=56, C=OC=256, G=8, Cg=32, K=5, pad=2.
//
// R24 = R23 (MFMA projection, 40.9us) minus its two measured diseases:
//  1) SPILL (VGPR 128=cap, WRITE 48.6MB vs 12.5 logical): MFMA loop split
//     into kv-pass (4 B-frags + 4 D live) then q-pass (2 + 2). A-frag
//     re-read ~9 LDS reads/wave - trivial.
//  2) BANK CONFLICTS (483K/dispatch): 64B-row xs16/wTs made b128 frag reads
//     8-way (banks {16r%32}); 32-dword kvs/qs rows made quarter-writes 4-way
//     (bank=lcol). Pad xs16/wTs rows to 40 halves (80B -> 2-way, free) and
//     kvs/qs rows to 33 words (bank=(row+col)%32).
// LDS: 11.25K + 7.5K + 18.6K + 8.25K = 45.6 KB. 2 barriers.
//
// MFMA geometry (m89-verified): D[144x96] = A[144x32] x B[32x96];
// A frag: lane(row=lw&15, k=(lw>>4)*8+j); B frag: B[k][col]=wTs[col][k];
// D: col=lane&15, row=(lane>>4)*4+reg. 16x16x32_f16, 54 MFMA/block.
//
// Register law (R1-R23): cap=256/N; spill signature: VGPR==cap AND
// WRITE >> 12.5MB. Precision: f16 proj + bf16 k,v/rel = 2.34e-2 measured;
// threshold 5.69e-2.

constexpr int TB = 4, TH = 56, TW = 56, TC = 256;
constexpr int G  = 8, CG = 32, PAD = 2;
constexpr int TILE = 8;
constexpr int HT = TILE + 2 * PAD;   // 12
constexpr int NT = TH / TILE;        // 7
constexpr int NPIX_HALO = HT * HT;   // 144
constexpr int XP = 40;               // padded row (halves) for xs16/wTs
constexpr int KP = 33;               // padded row (words) for kvs/qs
constexpr float LOG2E = 1.44269504088896340736f;

typedef __fp16 half2_t __attribute__((ext_vector_type(2)));
typedef __fp16 half8   __attribute__((ext_vector_type(8)));
typedef float  f32x4   __attribute__((ext_vector_type(4)));

__device__ __forceinline__ unsigned h2u(half2_t h) {
    union { half2_t h; unsigned u; } cv; cv.h = h; return cv.u;
}
__device__ __forceinline__ unsigned packbf(float k, float v) {
    return ((__float_as_uint(k) + 0x8000u) >> 16) |
           ((__float_as_uint(v) + 0x8000u) & 0xffff0000u);
}

__global__ __launch_bounds__(256, 2)
void fused_attn_conv_kernel(const float* __restrict__ x,
                            const float* __restrict__ wq,
                            const float* __restrict__ wk,
                            const float* __restrict__ wv,
                            const float* __restrict__ rel,
                            const float* __restrict__ qemb,
                            float* __restrict__ out) {
    __shared__ __align__(16) __fp16 xs16[NPIX_HALO][XP];  // 11.25 KB
    __shared__ __align__(16) __fp16 wTs[3 * CG][XP];      // 7.5 KB
    __shared__ unsigned kvs[NPIX_HALO][KP];               // 18.6 KB
    __shared__ float    qs[TILE * TILE][KP];              // 8.25 KB

    const int bid  = blockIdx.x;
    const int g    = bid & 7;
    const int tile = bid >> 3;
    const int tj   = tile % NT;
    const int ti   = (tile / NT) % NT;
    const int b    = tile / (NT * NT);

    const int t  = threadIdx.x;
    const int c  = t & 31;
    const int p0 = t >> 5;

    const int oc = g * CG + c;           // global out-channel (phase C)
    const int h0 = ti * TILE - PAD, w0 = tj * TILE - PAD;

    // ---- Stage x halo -> xs16 (f16 pairs; 2304 u32, 9/thread, coalesced).
    unsigned (*xsu)[XP / 2] = (unsigned(*)[XP / 2])xs16;
#pragma unroll
    for (int r = 0; r < 9; ++r) {
        const int f  = t + r * 256;          // 0..2303
        const int px = f >> 4, pr = f & 15;  // 16 channel-pairs per pixel
        const int hi = px / HT, hj = px % HT;
        const int gh = h0 + hi, gw = w0 + hj;
        unsigned val = 0u;
        if (gh >= 0 && gh < TH && gw >= 0 && gw < TW) {
            const float2 xv = *(const float2*)(x + (((size_t)b * TH + gh) * TW + gw) * TC
                                                 + g * CG + pr * 2);
            val = h2u(__builtin_amdgcn_cvt_pkrtz(xv.x, xv.y));
        }
        xsu[px][pr] = val;
    }

    // ---- Stage weights -> wTs (rows 0-31 wq, 32-63 wk, 64-95 wv).
    {
        unsigned (*wTu)[XP / 2] = (unsigned(*)[XP / 2])wTs;
        const float* wsrc[3] = {wq, wk, wv};
#pragma unroll
        for (int m = 0; m < 3; ++m) {
#pragma unroll
            for (int r = 0; r < 2; ++r) {
                const int f = t + r * 256;           // 0..511 float2 idx
                const int row = f >> 4, pr = f & 15; // row=oc 0..31
                const float2 wv2 = *(const float2*)(wsrc[m] + ((size_t)(g * CG + row)) * CG
                                                            + pr * 2);
                wTu[m * CG + row][pr] = h2u(__builtin_amdgcn_cvt_pkrtz(wv2.x, wv2.y));
            }
        }
    }

    __syncthreads();   // stage -> MFMA

    const int wvid = t >> 6, lw = t & 63;
    const int lcol = lw & 15;
    const int lko  = (lw >> 4) * 8;
    const f32x4 z4 = {0.f, 0.f, 0.f, 0.f};

    // ---- MFMA kv-pass: 4 B-frags + 4 D live (~40 regs peak).
    {
        const half8 bk0 = *(const half8*)&wTs[32 + lcol][lko];
        const half8 bk1 = *(const half8*)&wTs[48 + lcol][lko];
        const half8 bv0 = *(const half8*)&wTs[64 + lcol][lko];
        const half8 bv1 = *(const half8*)&wTs[80 + lcol][lko];
#pragma unroll 1
        for (int mt = wvid; mt < 9; mt += 4) {        // waves: 3/2/2/2 M-tiles
            const half8 a = *(const half8*)&xs16[mt * 16 + lcol][lko];
            const f32x4 dk0 = __builtin_amdgcn_mfma_f32_16x16x32_f16(a, bk0, z4, 0, 0, 0);
            const f32x4 dk1 = __builtin_amdgcn_mfma_f32_16x16x32_f16(a, bk1, z4, 0, 0, 0);
            const f32x4 dv0 = __builtin_amdgcn_mfma_f32_16x16x32_f16(a, bv0, z4, 0, 0, 0);
            const f32x4 dv1 = __builtin_amdgcn_mfma_f32_16x16x32_f16(a, bv1, z4, 0, 0, 0);
            const int prow = mt * 16 + ((lw >> 4) << 2);
#pragma unroll
            for (int j = 0; j < 4; ++j) {
                const int px = prow + j;
                kvs[px][lcol]      = packbf(dk0[j], dv0[j]);
                kvs[px][lcol + 16] = packbf(dk1[j], dv1[j]);
            }
        }
    }

    // ---- MFMA q-pass: 2 B-frags + 2 D live.
    {
        const half8 bq0 = *(const half8*)&wTs[ 0 + lcol][lko];
        const half8 bq1 = *(const half8*)&wTs[16 + lcol][lko];
        const float qeL = qemb[g * CG + lcol];
        const float qeH = qemb[g * CG + lcol + 16];
#pragma unroll 1
        for (int mt = wvid; mt < 9; mt += 4) {
            const half8 a = *(const half8*)&xs16[mt * 16 + lcol][lko];
            const f32x4 dq0 = __builtin_amdgcn_mfma_f32_16x16x32_f16(a, bq0, z4, 0, 0, 0);
            const f32x4 dq1 = __builtin_amdgcn_mfma_f32_16x16x32_f16(a, bq1, z4, 0, 0, 0);
            const int prow = mt * 16 + ((lw >> 4) << 2);
#pragma unroll
            for (int j = 0; j < 4; ++j) {
                const int px = prow + j;
                const int hi2 = px / HT, hj2 = px % HT;
                if (hi2 >= PAD && hi2 < PAD + TILE && hj2 >= PAD && hj2 < PAD + TILE) {
                    const int qp = (hi2 - PAD) * TILE + (hj2 - PAD);
                    qs[qp][lcol]      = (dq0[j] + qeL) * LOG2E;
                    qs[qp][lcol + 16] = (dq1[j] + qeH) * LOG2E;
                }
            }
        }
    }

    // rel row -> 13 packed bf16 pairs (even idx = low half, odd = high half)
    unsigned relp[13];
    {
        const float* rp = rel + (size_t)oc * 25;
#pragma unroll
        for (int i = 0; i < 12; ++i) {
            const unsigned lo = __float_as_uint(rp[2 * i])     + 0x8000u;
            const unsigned hi = __float_as_uint(rp[2 * i + 1]) + 0x8000u;
            relp[i] = (lo >> 16) | (hi & 0xffff0000u);
        }
        relp[12] = (__float_as_uint(rp[24]) + 0x8000u) >> 16;
    }

    __syncthreads();   // MFMA -> phase C

    // q (already *log2e) for this thread's 8 column pixels
    float qreg[8];
#pragma unroll
    for (int ii = 0; ii < 8; ++ii) qreg[ii] = qs[ii * TILE + p0][c];

    // ---- Phase C: monolithic row-streaming attention (champion structure).
    float s_[8], a_[8];
#pragma unroll
    for (int ii = 0; ii < 8; ++ii) { s_[ii] = 0.f; a_[ii] = 0.f; }

#pragma unroll
    for (int h = 0; h < HT; ++h) {
        float kr[5], vr[5];
#pragma unroll
        for (int j = 0; j < 5; ++j) {
            const unsigned u = kvs[h * HT + p0 + j][c];
            kr[j] = __uint_as_float(u << 16);          // bf16 k -> f32
            vr[j] = __uint_as_float(u & 0xffff0000u);  // bf16 v -> f32
        }
#pragma unroll
        for (int ii = 0; ii < 8; ++ii) {
            const int di = h - ii;               // compile-time after unroll
            if (di >= 0 && di < 5) {
                const float qv = qreg[ii];
#pragma unroll
                for (int j = 0; j < 5; ++j) {
                    const int idx = di * 5 + j;  // compile-time
                    const unsigned ru = relp[idx >> 1];
                    const float rl = __uint_as_float((idx & 1) ? (ru & 0xffff0000u)
                                                               : (ru << 16));
                    const float e = __builtin_amdgcn_exp2f(qv * (kr[j] + rl));
                    s_[ii] += e;
                    a_[ii] = fmaf(e, vr[j], a_[ii]);
                }
            }
        }
    }

#pragma unroll
    for (int ii = 0; ii < 8; ++ii) {
        const int gh = ti * TILE + ii, gw = tj * TILE + p0;
        out[(((size_t)b * TH + gh) * TW + gw) * TC + g * CG + c] =
            a_[ii] * __builtin_amdgcn_rcpf(s_[ii]);
    }
}

extern "C" void kernel_launch(void* const* d_in, const int* in_sizes, int n_in,
                              void* d_out, int out_size, void* d_ws, size_t ws_size,
                              hipStream_t stream) {
    const float* x    = (const float*)d_in[0];
    const float* wq   = (const float*)d_in[1];
    const float* wk   = (const float*)d_in[2];
    const float* wv   = (const float*)d_in[3];
    const float* rel  = (const float*)d_in[4];
    const float* qemb = (const float*)d_in[5];
    float* out = (float*)d_out;

    const int nblocks = TB * NT * NT * G;   // 4*7*7*8 = 1568
    hipLaunchKernelGGL(fused_attn_conv_kernel, dim3(nblocks), dim3(256), 0, stream,
                       x, wq, wk, wv, rel, qemb, out);
}